// Round 4
// baseline (4116.268 us; speedup 1.0000x reference)
//
#include <hip/hip_runtime.h>

// LSTM T=512 B=64 IN=512 H=512 L=2, fp32 in/out.
// Round 9: R8 structure with MFMA operands SWAPPED: acc = mfma(W, h, acc)
// so D[M=Wrow][N=batch]. Lane (l31,lh) then holds, for batch l31, all four
// gates g=r>>2 at local cols (r&3)+4*lh -- gate math is lane-local (this is
// what R8's epilogue/publish formulas assumed; with mfma(h,W) the layout was
// transposed => R8's 0.565 absmax).
// Structure: fragment-granular consumption + single-wave epilogue.
// h layout piece16[bt][i][lane] (16B = one MFMA B-fragment): consumer frag i
// depends ONLY on producer blocks {2i,2i+1}. Consumer polls 64 flags (2/lane,
// one ballot -> uniform mask) and MFMAs fragments as producers land.
// kh1 wave owns gates+creg in-register, publishes its own 8B piece +
// per-(block,bt) flag; ONE barrier/step (kh0 partial handoff, dbuf LDS).

typedef unsigned short u16;
typedef unsigned int u32;
typedef unsigned long long u64;
typedef __attribute__((ext_vector_type(8))) short bf16x8;
typedef __attribute__((ext_vector_type(4))) float floatx4;
typedef __attribute__((ext_vector_type(16))) float floatx16;

#define T_ 512
#define B_ 64
#define H_ 512
#define BH (B_ * H_)

__device__ __forceinline__ u16 f2bf(float f) {
  u32 u = __float_as_uint(f);
  u32 r = (u + 0x7fffu + ((u >> 16) & 1u)) >> 16;  // RNE
  return (u16)r;
}

__device__ __forceinline__ float sigm(float x) { return 1.f / (1.f + __expf(-x)); }

__device__ __forceinline__ float tanh_(float x) {
  float ax = fabsf(x);
  float e = __expf(-2.f * ax);
  float t = (1.f - e) / (1.f + e);
  return copysignf(t, x);
}

// Wcat[l][row 0..2047][k 0..1023] bf16: k<512 from Wx, k>=512 from Wh.
__global__ void conv_w_kernel(const float* __restrict__ Wx, const float* __restrict__ Wh,
                              u16* __restrict__ Wcat) {
  int i = blockIdx.x * 256 + threadIdx.x;
  int base = i * 4;
  int k = base & 1023;
  int row = base >> 10;
  const float* src = (k < 512) ? (Wx + row * 512 + k) : (Wh + row * 512 + (k - 512));
  float4 v = *(const float4*)src;
  uint2 p;
  p.x = (u32)f2bf(v.x) | ((u32)f2bf(v.y) << 16);
  p.y = (u32)f2bf(v.z) | ((u32)f2bf(v.w) << 16);
  *(uint2*)(Wcat + base) = p;
}

// xT piece16[t][bt][i][L] (16B) = x_bf16[t][bt*32+(L&31)][16i+8*(L>>5) .. +8)
__global__ void conv_x_kernel(const float* __restrict__ x, u16* __restrict__ xb) {
  int p = blockIdx.x * 256 + threadIdx.x;  // 2,097,152 pieces
  int L = p & 63;
  int i = (p >> 6) & 31;
  int bt = (p >> 11) & 1;
  int t = p >> 12;
  int r = bt * 32 + (L & 31);
  int k0 = i * 16 + (L >> 5) * 8;
  const float* s = x + ((size_t)(t * 64 + r) * 512 + k0);
  float4 v0 = *(const float4*)s;
  float4 v1 = *(const float4*)(s + 4);
  uint4 q;
  q.x = (u32)f2bf(v0.x) | ((u32)f2bf(v0.y) << 16);
  q.y = (u32)f2bf(v0.z) | ((u32)f2bf(v0.w) << 16);
  q.z = (u32)f2bf(v1.x) | ((u32)f2bf(v1.y) << 16);
  q.w = (u32)f2bf(v1.z) | ((u32)f2bf(v1.w) << 16);
  *(uint4*)(xb + (size_t)p * 8) = q;
}

__global__ void init_flags(u32* flags) {
  if (threadIdx.x < 256) flags[threadIdx.x] = 0;
}

__device__ __forceinline__ u32 aload32(const u32* p) {
  return __hip_atomic_load(p, __ATOMIC_RELAXED, __HIP_MEMORY_SCOPE_AGENT);
}
__device__ __forceinline__ u64 aload64(const u64* p) {
  return __hip_atomic_load(p, __ATOMIC_RELAXED, __HIP_MEMORY_SCOPE_AGENT);
}
__device__ __forceinline__ void astore32(u32* p, u32 v) {
  __hip_atomic_store(p, v, __ATOMIC_RELAXED, __HIP_MEMORY_SCOPE_AGENT);
}
__device__ __forceinline__ void astore64(u64* p, u64 v) {
  __hip_atomic_store(p, v, __ATOMIC_RELAXED, __HIP_MEMORY_SCOPE_AGENT);
}

// Whole-wave poll: lane l watches f[l], exit when all 64 >= target.
__device__ __forceinline__ void wave_wait(const u32* f, u32 target, int lane) {
  while (!__all((int)(aload32(f + lane) >= target))) __builtin_amdgcn_s_sleep(1);
}

// Fragment-granular consume: hb = u64 base of [bt] half of a 64KB slot
// (piece p at hb+2p, p = i*64+lane); fb = 64 producer flags for this bt.
// Frag i ready iff flags[2i] and [2i+1] >= tgt (lane L checks pair 2*(L&31)).
// MFMA operand order: acc = mfma(w[i], h_frag, acc)  -> D[Wrow][batch].
__device__ __forceinline__ void consume(const u64* __restrict__ hb, const u32* __restrict__ fb,
                                        u32 tgt, const bf16x8* w, floatx16& acc, int lane,
                                        int l31) {
  const u32* fp = fb + 2 * l31;
  u32 done = 0;
  for (;;) {
    u32 a = aload32(fp);
    u32 b = aload32(fp + 1);
    u32 frm = (u32)__ballot((int)(a >= tgt && b >= tgt));
    u32 newm = frm & ~done;
    if (newm) {
      u64 q0[32], q1[32];
#pragma unroll
      for (int i = 0; i < 32; ++i)
        if ((newm >> i) & 1) {
          q0[i] = aload64(hb + i * 128 + lane * 2);
          q1[i] = aload64(hb + i * 128 + lane * 2 + 1);
        }
#pragma unroll
      for (int i = 0; i < 32; ++i)
        if ((newm >> i) & 1) {
          union {
            u64 qq[2];
            bf16x8 v;
          } u;
          u.qq[0] = q0[i];
          u.qq[1] = q1[i];
          acc = __builtin_amdgcn_mfma_f32_32x32x16_bf16(w[i], u.v, acc, 0, 0, 0);
        }
      done |= newm;
    }
    if (done == 0xFFFFFFFFu) break;
    __builtin_amdgcn_s_sleep(1);
  }
}

// 128 blocks x 256 threads (1 block/CU). unit=blockIdx&1, cg=blockIdx>>1.
// Wave: bt=wave&1, kh=wave>>1. kh0 = early input (x / h0_t), kh1 = own-layer
// recurrence + gates + publish. flags: f0[2][64], f1[2][64] per (bt, block).
__global__ __launch_bounds__(256, 1) void lstm_persist(
    const u16* __restrict__ Wcat, const float* __restrict__ bh,
    const u16* __restrict__ xb, u16* __restrict__ h0s, u16* __restrict__ h1s,
    u32* flags, float* __restrict__ out) {
  const int unit = blockIdx.x & 1;
  const int cg = blockIdx.x >> 1;
  const int colbase = cg * 8;
  const int tid = threadIdx.x;
  const int wave = tid >> 6;
  const int bt = wave & 1;
  const int kh = wave >> 1;
  const int lane = tid & 63;
  const int l31 = lane & 31;
  const int lh = lane >> 5;

  __shared__ float ldsp[2 * 2 * 4 * 256];  // [buf][bt][rg][lane*4] = 16 KB

  // ---- W fragments into VGPRs (loop-invariant). A[row][k]: row=lane&31 -> W
  // row rp; k = kh*512 + i*16 + lh*8 + j (8 contiguous k -> one b128).
  bf16x8 w[32];
  {
    const int rp = l31;
    const u16* wbase = Wcat + ((size_t)unit * 2048 + (rp >> 3) * 512 + colbase + (rp & 7)) * 1024 +
                       kh * 512 + lh * 8;
#pragma unroll
    for (int i = 0; i < 32; ++i) w[i] = *(const bf16x8*)(wbase + i * 16);
  }

  // kh1-wave gate state (D[M=Wrow][N=batch]): lane (bt, l31, lh) owns batch
  // b = bt*32+l31, cols colbase + 4*lh + q (q=0..3); acc reg r = g*4+q
  // (Wrow = (r&3)+8*(r>>2)+4*lh = g*8 + (4*lh+q)).
  float bias[4][4];
#pragma unroll
  for (int g = 0; g < 4; ++g)
#pragma unroll
    for (int q = 0; q < 4; ++q)
      bias[g][q] = bh[unit * 2048 + g * 512 + colbase + 4 * lh + q];
  float creg[4] = {0.f, 0.f, 0.f, 0.f};

  u32* f0 = flags;        // [bt*64 + cg]
  u32* f1 = flags + 128;  // [bt*64 + cg]
  u32* myflag = (unit ? f1 : f0) + bt * 64 + cg;

  const size_t out_h_base = (size_t)T_ * BH;
  const size_t out_c_base = out_h_base + 2 * (size_t)BH;
  const int orow = bt * 32 + l31;
  const int ocol = colbase + 4 * lh;

  for (int t = 0; t < T_; ++t) {
    floatx16 acc = {0.f, 0.f, 0.f, 0.f, 0.f, 0.f, 0.f, 0.f,
                    0.f, 0.f, 0.f, 0.f, 0.f, 0.f, 0.f, 0.f};
    const int buf = t & 1;
    float* lp = ldsp + (buf * 2 + bt) * 1024 + lane * 4;

    if (kh == 0) {
      if (unit == 0) {
        // x-half: plain dense loads from transposed xb (no dependency).
        const bf16x8* xp = (const bf16x8*)xb + (size_t)t * 4096 + bt * 2048 + lane;
#pragma unroll
        for (int i = 0; i < 32; ++i)
          acc = __builtin_amdgcn_mfma_f32_32x32x16_bf16(w[i], xp[i * 64], acc, 0, 0, 0);
      } else {
        // h0_t half (Wx1): the cross-layer hop; fragment-granular.
        consume((const u64*)h0s + (size_t)(t & 3) * 8192 + bt * 4096, f0 + bt * 64,
                (u32)(t + 1), w, acc, lane, l31);
      }
      // partial -> LDS (double-buffered), one barrier per step.
#pragma unroll
      for (int rg = 0; rg < 4; ++rg)
        *(floatx4*)(lp + rg * 256) =
            floatx4{acc[rg * 4 + 0], acc[rg * 4 + 1], acc[rg * 4 + 2], acc[rg * 4 + 3]};
      __syncthreads();
    } else {
      // kh1: own-layer recurrence (h0_{t-1} / h1_{t-1}), fragment-granular.
      if (t > 0) {
        const u64* hb;
        const u32* fb;
        if (unit == 0) {
          hb = (const u64*)h0s + (size_t)((t - 1) & 3) * 8192 + bt * 4096;
          fb = f0 + bt * 64;
        } else {
          hb = (const u64*)h1s + (size_t)((t - 1) & 3) * 8192 + bt * 4096;
          fb = f1 + bt * 64;
        }
        consume(hb, fb, (u32)t, w, acc, lane, l31);
      }
      __syncthreads();
      // add kh0 partial from LDS (same lane<->element mapping both waves)
#pragma unroll
      for (int rg = 0; rg < 4; ++rg) {
        floatx4 p = *(const floatx4*)(lp + rg * 256);
        acc[rg * 4 + 0] += p.x;
        acc[rg * 4 + 1] += p.y;
        acc[rg * 4 + 2] += p.z;
        acc[rg * 4 + 3] += p.w;
      }
      // gates in-register: gate g = acc[g*4+q], col q (of this lane's 4)
      float hn[4], cn[4];
#pragma unroll
      for (int q = 0; q < 4; ++q) {
        float pi = acc[q] + bias[0][q];
        float pf = acc[4 + q] + bias[1][q];
        float pg = acc[8 + q] + bias[2][q];
        float po = acc[12 + q] + bias[3][q];
        float ig = sigm(pi);
        float fg = sigm(pf);
        float gg = tanh_(pg);
        float og = sigm(po);
        cn[q] = fg * creg[q] + ig * gg;
        hn[q] = og * tanh_(cn[q]);
        creg[q] = cn[q];
      }

      // slot-reuse guard: unit1's kh0-bt waves must have consumed h0_{t-4}
      // (f1[bt][*] >= t-3 implies their block passed barrier t-3).
      if (unit == 0 && t >= 4) wave_wait(f1 + bt * 64, (u32)(t - 3), lane);

      // publish own 8B piece: piece p = bt*2048 + (cg>>1)*64 + (cg&1)*32 + l31,
      // u64 half lh. Then drain, release own flag.
      u64 pack = (u64)f2bf(hn[0]) | ((u64)f2bf(hn[1]) << 16) | ((u64)f2bf(hn[2]) << 32) |
                 ((u64)f2bf(hn[3]) << 48);
      u64* slot = (u64*)((unit ? h1s : h0s) + (size_t)(t & 3) * BH);
      astore64(slot + ((size_t)bt * 2048 + (cg >> 1) * 64 + (cg & 1) * 32 + l31) * 2 + lh, pack);
      asm volatile("s_waitcnt vmcnt(0)" ::: "memory");
      astore32(myflag, (u32)(t + 1));

      // off-chain d_out stores AFTER flag release.
      if (unit == 1)
        *(float4*)(out + (size_t)t * BH + (size_t)orow * 512 + ocol) =
            make_float4(hn[0], hn[1], hn[2], hn[3]);
      if (t == T_ - 1) {
        *(float4*)(out + out_h_base + (size_t)unit * BH + (size_t)orow * 512 + ocol) =
            make_float4(hn[0], hn[1], hn[2], hn[3]);
        *(float4*)(out + out_c_base + (size_t)unit * BH + (size_t)orow * 512 + ocol) =
            make_float4(cn[0], cn[1], cn[2], cn[3]);
      }
    }
  }
}

extern "C" void kernel_launch(void* const* d_in, const int* in_sizes, int n_in,
                              void* d_out, int out_size, void* d_ws, size_t ws_size,
                              hipStream_t stream) {
  const float* x = (const float*)d_in[0];
  const float* Wx = (const float*)d_in[1];
  const float* Wh = (const float*)d_in[2];
  const float* bh = (const float*)d_in[3];
  float* out = (float*)d_out;
  char* ws = (char*)d_ws;

  u16* Wcat = (u16*)ws;                                  // 8,388,608 B
  u16* xb = (u16*)(ws + 8388608);                        // 33,554,432 B
  u16* h0s = (u16*)(ws + 8388608 + 33554432);            // 262,144 B (4 slots)
  u16* h1s = (u16*)(ws + 8388608 + 33554432 + 262144);   // 262,144 B
  u32* flags = (u32*)(ws + 8388608 + 33554432 + 2 * 262144);  // 1,024 B

  conv_w_kernel<<<4096, 256, 0, stream>>>(Wx, Wh, Wcat);
  conv_x_kernel<<<8192, 256, 0, stream>>>(x, xb);
  init_flags<<<1, 256, 0, stream>>>(flags);
  lstm_persist<<<128, 256, 0, stream>>>(Wcat, bh, xb, h0s, h1s, flags, out);
}

// Round 7
// 3932.750 us; speedup vs baseline: 1.0467x; 1.0467x over previous
//
#include <hip/hip_runtime.h>

// LSTM T=512 B=64 IN=512 H=512 L=2, fp32 in/out.
// Round 12: back to the proven flag-acquire protocol (R7), fused with R9's
// verified lean epilogue. Per block: 4 waves (bt, kh). kh0 = early input
// (x-half for unit0 / h0_t hop for unit1), kh1 = own-layer recurrence +
// in-register gates + publish. Consume = wave_wait(64 flags) -> ONE dense
// pass of 64 in-flight aload64 (no ballot, no retry reloads). Publish =
// 8B/lane 16B-piece layout (R9-verified), vmcnt(0), lane0 flag. 1 barrier
// per step (double-buffered LDS partial handoff). Out stores after flag.

typedef unsigned short u16;
typedef unsigned int u32;
typedef unsigned long long u64;
typedef __attribute__((ext_vector_type(8))) short bf16x8;
typedef __attribute__((ext_vector_type(4))) float floatx4;
typedef __attribute__((ext_vector_type(16))) float floatx16;

#define T_ 512
#define B_ 64
#define H_ 512
#define BH (B_ * H_)

__device__ __forceinline__ u16 f2bf(float f) {
  u32 u = __float_as_uint(f);
  u32 r = (u + 0x7fffu + ((u >> 16) & 1u)) >> 16;  // RNE
  return (u16)r;
}

__device__ __forceinline__ float sigm(float x) { return 1.f / (1.f + __expf(-x)); }

__device__ __forceinline__ float tanh_(float x) {
  float ax = fabsf(x);
  float e = __expf(-2.f * ax);
  float t = (1.f - e) / (1.f + e);
  return copysignf(t, x);
}

// Wcat[l][row 0..2047][k 0..1023] bf16: k<512 from Wx, k>=512 from Wh.
__global__ void conv_w_kernel(const float* __restrict__ Wx, const float* __restrict__ Wh,
                              u16* __restrict__ Wcat) {
  int i = blockIdx.x * 256 + threadIdx.x;
  int base = i * 4;
  int k = base & 1023;
  int row = base >> 10;
  const float* src = (k < 512) ? (Wx + row * 512 + k) : (Wh + row * 512 + (k - 512));
  float4 v = *(const float4*)src;
  uint2 p;
  p.x = (u32)f2bf(v.x) | ((u32)f2bf(v.y) << 16);
  p.y = (u32)f2bf(v.z) | ((u32)f2bf(v.w) << 16);
  *(uint2*)(Wcat + base) = p;
}

// xT piece16[t][bt][i][L] (16B) = x_bf16[t][bt*32+(L&31)][16i+8*(L>>5) .. +8)
__global__ void conv_x_kernel(const float* __restrict__ x, u16* __restrict__ xb) {
  int p = blockIdx.x * 256 + threadIdx.x;  // 2,097,152 pieces
  int L = p & 63;
  int i = (p >> 6) & 31;
  int bt = (p >> 11) & 1;
  int t = p >> 12;
  int r = bt * 32 + (L & 31);
  int k0 = i * 16 + (L >> 5) * 8;
  const float* s = x + ((size_t)(t * 64 + r) * 512 + k0);
  float4 v0 = *(const float4*)s;
  float4 v1 = *(const float4*)(s + 4);
  uint4 q;
  q.x = (u32)f2bf(v0.x) | ((u32)f2bf(v0.y) << 16);
  q.y = (u32)f2bf(v0.z) | ((u32)f2bf(v0.w) << 16);
  q.z = (u32)f2bf(v1.x) | ((u32)f2bf(v1.y) << 16);
  q.w = (u32)f2bf(v1.z) | ((u32)f2bf(v1.w) << 16);
  *(uint4*)(xb + (size_t)p * 8) = q;
}

__global__ void init_flags(u32* flags) {
  if (threadIdx.x < 256) flags[threadIdx.x] = 0;
}

__device__ __forceinline__ u32 aload32(const u32* p) {
  return __hip_atomic_load(p, __ATOMIC_RELAXED, __HIP_MEMORY_SCOPE_AGENT);
}
__device__ __forceinline__ u64 aload64(const u64* p) {
  return __hip_atomic_load(p, __ATOMIC_RELAXED, __HIP_MEMORY_SCOPE_AGENT);
}
__device__ __forceinline__ void astore32(u32* p, u32 v) {
  __hip_atomic_store(p, v, __ATOMIC_RELAXED, __HIP_MEMORY_SCOPE_AGENT);
}
__device__ __forceinline__ void astore64(u64* p, u64 v) {
  __hip_atomic_store(p, v, __ATOMIC_RELAXED, __HIP_MEMORY_SCOPE_AGENT);
}

// Whole-wave poll: lane l watches f[l] (64 producer flags), exit when all >= target.
__device__ __forceinline__ void wave_wait(const u32* f, u32 target, int lane) {
  while (!__all((int)(aload32(f + lane) >= target))) __builtin_amdgcn_s_sleep(1);
}

// Dense consume after flag-acquire: hb = u64 base of [slot][bt] plane
// (4096 u64 = 32KB). Piece (i, lane) = u64s [2*(i*64+lane), +1]. All 64
// loads issued in flight (one RT), then 32 MFMAs: acc = mfma(W, h).
__device__ __forceinline__ void consume_dense(const u64* __restrict__ hb, const bf16x8* w,
                                              floatx16& acc, int lane) {
  u64 q0[32], q1[32];
#pragma unroll
  for (int i = 0; i < 32; ++i) {
    q0[i] = aload64(hb + i * 128 + lane * 2);
    q1[i] = aload64(hb + i * 128 + lane * 2 + 1);
  }
#pragma unroll
  for (int i = 0; i < 32; ++i) {
    union {
      u64 qq[2];
      bf16x8 v;
    } u;
    u.qq[0] = q0[i];
    u.qq[1] = q1[i];
    acc = __builtin_amdgcn_mfma_f32_32x32x16_bf16(w[i], u.v, acc, 0, 0, 0);
  }
}

// 128 blocks x 256 threads (1 block/CU). unit=blockIdx&1, cg=blockIdx>>1.
// flags: f0[2][64], f1[2][64] indexed [bt*64 + cg].
__global__ __launch_bounds__(256, 1) void lstm_persist(
    const u16* __restrict__ Wcat, const float* __restrict__ bh,
    const u16* __restrict__ xb, u16* __restrict__ h0s, u16* __restrict__ h1s,
    u32* flags, float* __restrict__ out) {
  const int unit = blockIdx.x & 1;
  const int cg = blockIdx.x >> 1;
  const int colbase = cg * 8;
  const int tid = threadIdx.x;
  const int wave = tid >> 6;
  const int bt = wave & 1;
  const int kh = wave >> 1;
  const int lane = tid & 63;
  const int l31 = lane & 31;
  const int lh = lane >> 5;

  __shared__ float ldsp[2 * 2 * 4 * 256];  // [buf][bt][rg][lane*4] = 16 KB

  // ---- W fragments into VGPRs (loop-invariant). A[row][k]: row=lane&31 -> W
  // row rp; k = kh*512 + i*16 + lh*8 + j (8 contiguous k -> one b128).
  bf16x8 w[32];
  {
    const int rp = l31;
    const u16* wbase = Wcat + ((size_t)unit * 2048 + (rp >> 3) * 512 + colbase + (rp & 7)) * 1024 +
                       kh * 512 + lh * 8;
#pragma unroll
    for (int i = 0; i < 32; ++i) w[i] = *(const bf16x8*)(wbase + i * 16);
  }

  // kh1-wave gate state (D[M=Wrow][N=batch]): lane (bt, l31, lh) owns batch
  // b = bt*32+l31, cols colbase + 4*lh + q (q=0..3); acc reg r = g*4+q
  // (Wrow = (r&3)+8*(r>>2)+4*lh = g*8 + (4*lh+q)).
  float bias[4][4];
#pragma unroll
  for (int g = 0; g < 4; ++g)
#pragma unroll
    for (int q = 0; q < 4; ++q)
      bias[g][q] = bh[unit * 2048 + g * 512 + colbase + 4 * lh + q];
  float creg[4] = {0.f, 0.f, 0.f, 0.f};

  u32* f0 = flags;        // [bt*64 + cg]
  u32* f1 = flags + 128;  // [bt*64 + cg]
  u32* myflag = (unit ? f1 : f0) + bt * 64 + cg;

  const size_t out_h_base = (size_t)T_ * BH;
  const size_t out_c_base = out_h_base + 2 * (size_t)BH;
  const int orow = bt * 32 + l31;
  const int ocol = colbase + 4 * lh;

  // publish piece index (R9-verified): p = bt*2048 + (cg>>1)*64 + (cg&1)*32
  // + l31, u64 half lh.
  const size_t pub_idx =
      ((size_t)bt * 2048 + (cg >> 1) * 64 + (cg & 1) * 32 + l31) * 2 + lh;

  for (int t = 0; t < T_; ++t) {
    floatx16 acc = {0.f, 0.f, 0.f, 0.f, 0.f, 0.f, 0.f, 0.f,
                    0.f, 0.f, 0.f, 0.f, 0.f, 0.f, 0.f, 0.f};
    const int buf = t & 1;
    float* lp = ldsp + (buf * 2 + bt) * 1024 + lane * 4;

    if (kh == 0) {
      if (unit == 0) {
        // x-half: plain dense loads from transposed xb (no dependency).
        const bf16x8* xp = (const bf16x8*)xb + (size_t)t * 4096 + bt * 2048 + lane;
#pragma unroll
        for (int i = 0; i < 32; ++i)
          acc = __builtin_amdgcn_mfma_f32_32x32x16_bf16(w[i], xp[i * 64], acc, 0, 0, 0);
      } else {
        // h0_t half (Wx1): the cross-layer hop.
        wave_wait(f0 + bt * 64, (u32)(t + 1), lane);
        consume_dense((const u64*)h0s + (size_t)(t & 3) * 8192 + (size_t)bt * 4096, w, acc, lane);
      }
      // partial -> LDS (double-buffered), one barrier per step.
#pragma unroll
      for (int rg = 0; rg < 4; ++rg)
        *(floatx4*)(lp + rg * 256) =
            floatx4{acc[rg * 4 + 0], acc[rg * 4 + 1], acc[rg * 4 + 2], acc[rg * 4 + 3]};
      __syncthreads();
    } else {
      // kh1: own-layer recurrence (h0_{t-1} / h1_{t-1}).
      if (t > 0) {
        if (unit == 0) {
          wave_wait(f0 + bt * 64, (u32)t, lane);
          consume_dense((const u64*)h0s + (size_t)((t - 1) & 3) * 8192 + (size_t)bt * 4096, w,
                        acc, lane);
        } else {
          wave_wait(f1 + bt * 64, (u32)t, lane);
          consume_dense((const u64*)h1s + (size_t)((t - 1) & 3) * 8192 + (size_t)bt * 4096, w,
                        acc, lane);
        }
      }
      __syncthreads();
      // add kh0 partial from LDS (same lane<->element mapping both waves)
#pragma unroll
      for (int rg = 0; rg < 4; ++rg) {
        floatx4 p = *(const floatx4*)(lp + rg * 256);
        acc[rg * 4 + 0] += p.x;
        acc[rg * 4 + 1] += p.y;
        acc[rg * 4 + 2] += p.z;
        acc[rg * 4 + 3] += p.w;
      }
      // gates in-register: gate g = acc[g*4+q], col q (of this lane's 4)
      float hn[4], cn[4];
#pragma unroll
      for (int q = 0; q < 4; ++q) {
        float pi = acc[q] + bias[0][q];
        float pf = acc[4 + q] + bias[1][q];
        float pg = acc[8 + q] + bias[2][q];
        float po = acc[12 + q] + bias[3][q];
        float ig = sigm(pi);
        float fg = sigm(pf);
        float gg = tanh_(pg);
        float og = sigm(po);
        cn[q] = fg * creg[q] + ig * gg;
        hn[q] = og * tanh_(cn[q]);
        creg[q] = cn[q];
      }

      // slot-reuse guard (unit0 only, R9-proven): before overwriting h0 slot
      // t&3 (holds h0_{t-4}, read by unit1 kh0 at step t-4), need unit1 past
      // step t-4 (f1[bt] >= t-3).
      if (unit == 0 && t >= 4) wave_wait(f1 + bt * 64, (u32)(t - 3), lane);

      // publish own 8B piece, drain, lane0 releases this wave's flag.
      u64 pack = (u64)f2bf(hn[0]) | ((u64)f2bf(hn[1]) << 16) | ((u64)f2bf(hn[2]) << 32) |
                 ((u64)f2bf(hn[3]) << 48);
      u64* slot = (u64*)((unit ? h1s : h0s) + (size_t)(t & 3) * BH);
      astore64(slot + pub_idx, pack);
      asm volatile("s_waitcnt vmcnt(0)" ::: "memory");
      if (lane == 0) astore32(myflag, (u32)(t + 1));

      // off-chain d_out stores AFTER flag release.
      if (unit == 1)
        *(float4*)(out + (size_t)t * BH + (size_t)orow * 512 + ocol) =
            make_float4(hn[0], hn[1], hn[2], hn[3]);
      if (t == T_ - 1) {
        *(float4*)(out + out_h_base + (size_t)unit * BH + (size_t)orow * 512 + ocol) =
            make_float4(hn[0], hn[1], hn[2], hn[3]);
        *(float4*)(out + out_c_base + (size_t)unit * BH + (size_t)orow * 512 + ocol) =
            make_float4(cn[0], cn[1], cn[2], cn[3]);
      }
    }
  }
}

extern "C" void kernel_launch(void* const* d_in, const int* in_sizes, int n_in,
                              void* d_out, int out_size, void* d_ws, size_t ws_size,
                              hipStream_t stream) {
  const float* x = (const float*)d_in[0];
  const float* Wx = (const float*)d_in[1];
  const float* Wh = (const float*)d_in[2];
  const float* bh = (const float*)d_in[3];
  float* out = (float*)d_out;
  char* ws = (char*)d_ws;

  u16* Wcat = (u16*)ws;                                  // 8,388,608 B
  u16* xb = (u16*)(ws + 8388608);                        // 33,554,432 B
  u16* h0s = (u16*)(ws + 8388608 + 33554432);            // 262,144 B (4 slots)
  u16* h1s = (u16*)(ws + 8388608 + 33554432 + 262144);   // 262,144 B
  u32* flags = (u32*)(ws + 8388608 + 33554432 + 2 * 262144);  // 1,024 B

  conv_w_kernel<<<4096, 256, 0, stream>>>(Wx, Wh, Wcat);
  conv_x_kernel<<<8192, 256, 0, stream>>>(x, xb);
  init_flags<<<1, 256, 0, stream>>>(flags);
  lstm_persist<<<128, 256, 0, stream>>>(Wcat, bh, xb, h0s, h1s, flags, out);
}

// Round 8
// 3354.212 us; speedup vs baseline: 1.2272x; 1.1725x over previous
//
#include <hip/hip_runtime.h>

// LSTM T=512 B=64 IN=512 H=512 L=2, fp32 in/out.
// Round 13: R12 dataflow with PRIVATIZED flag mailboxes + hard spin.
// Hypothesis under test: the ~7us/step floor is flag-cacheline contention
// (384 waves polling 8 shared lines agent-scope) and/or DPM clock droop from
// s_sleep idling. Change: pf[consumer 128][bt 2][producer 64] private rows --
// each poll loop reads its OWN 256B (nobody else reads it; one producer lane
// writes each word); producers fan out flags with 2 stores/lane after the
// data drain. Polls busy-spin (no s_sleep) to kill discovery quantization
// and keep clocks up. Everything else identical to R12 (verified): W in
// VGPRs, mfma(W,h) D[Wrow][batch], dense consume, lean in-register epilogue,
// 1 barrier/step, 16B-piece publish layout, 4-slot h buffers, lag guard.

typedef unsigned short u16;
typedef unsigned int u32;
typedef unsigned long long u64;
typedef __attribute__((ext_vector_type(8))) short bf16x8;
typedef __attribute__((ext_vector_type(4))) float floatx4;
typedef __attribute__((ext_vector_type(16))) float floatx16;

#define T_ 512
#define B_ 64
#define H_ 512
#define BH (B_ * H_)

__device__ __forceinline__ u16 f2bf(float f) {
  u32 u = __float_as_uint(f);
  u32 r = (u + 0x7fffu + ((u >> 16) & 1u)) >> 16;  // RNE
  return (u16)r;
}

__device__ __forceinline__ float sigm(float x) { return 1.f / (1.f + __expf(-x)); }

__device__ __forceinline__ float tanh_(float x) {
  float ax = fabsf(x);
  float e = __expf(-2.f * ax);
  float t = (1.f - e) / (1.f + e);
  return copysignf(t, x);
}

// Wcat[l][row 0..2047][k 0..1023] bf16: k<512 from Wx, k>=512 from Wh.
__global__ void conv_w_kernel(const float* __restrict__ Wx, const float* __restrict__ Wh,
                              u16* __restrict__ Wcat) {
  int i = blockIdx.x * 256 + threadIdx.x;
  int base = i * 4;
  int k = base & 1023;
  int row = base >> 10;
  const float* src = (k < 512) ? (Wx + row * 512 + k) : (Wh + row * 512 + (k - 512));
  float4 v = *(const float4*)src;
  uint2 p;
  p.x = (u32)f2bf(v.x) | ((u32)f2bf(v.y) << 16);
  p.y = (u32)f2bf(v.z) | ((u32)f2bf(v.w) << 16);
  *(uint2*)(Wcat + base) = p;
}

// xT piece16[t][bt][i][L] (16B) = x_bf16[t][bt*32+(L&31)][16i+8*(L>>5) .. +8)
__global__ void conv_x_kernel(const float* __restrict__ x, u16* __restrict__ xb) {
  int p = blockIdx.x * 256 + threadIdx.x;  // 2,097,152 pieces
  int L = p & 63;
  int i = (p >> 6) & 31;
  int bt = (p >> 11) & 1;
  int t = p >> 12;
  int r = bt * 32 + (L & 31);
  int k0 = i * 16 + (L >> 5) * 8;
  const float* s = x + ((size_t)(t * 64 + r) * 512 + k0);
  float4 v0 = *(const float4*)s;
  float4 v1 = *(const float4*)(s + 4);
  uint4 q;
  q.x = (u32)f2bf(v0.x) | ((u32)f2bf(v0.y) << 16);
  q.y = (u32)f2bf(v0.z) | ((u32)f2bf(v0.w) << 16);
  q.z = (u32)f2bf(v1.x) | ((u32)f2bf(v1.y) << 16);
  q.w = (u32)f2bf(v1.z) | ((u32)f2bf(v1.w) << 16);
  *(uint4*)(xb + (size_t)p * 8) = q;
}

// zero 2 x 128KB private flag arrays (65536 u32).
__global__ void init_flags(u32* pf) {
  pf[blockIdx.x * 256 + threadIdx.x] = 0;
}

__device__ __forceinline__ u32 aload32(const u32* p) {
  return __hip_atomic_load(p, __ATOMIC_RELAXED, __HIP_MEMORY_SCOPE_AGENT);
}
__device__ __forceinline__ u64 aload64(const u64* p) {
  return __hip_atomic_load(p, __ATOMIC_RELAXED, __HIP_MEMORY_SCOPE_AGENT);
}
__device__ __forceinline__ void astore32(u32* p, u32 v) {
  __hip_atomic_store(p, v, __ATOMIC_RELAXED, __HIP_MEMORY_SCOPE_AGENT);
}
__device__ __forceinline__ void astore64(u64* p, u64 v) {
  __hip_atomic_store(p, v, __ATOMIC_RELAXED, __HIP_MEMORY_SCOPE_AGENT);
}

// Private-row poll: lane l spins on f[l] (this block's own 256B row).
__device__ __forceinline__ void wave_wait(const u32* f, u32 target, int lane) {
  while (!__all((int)(aload32(f + lane) >= target))) {
  }
}

// Dense consume after flag-acquire: hb = u64 base of [slot][bt] plane
// (4096 u64 = 32KB). Piece (i, lane) = u64s [2*(i*64+lane), +1]. All 64
// loads issued in flight (one RT), then 32 MFMAs: acc = mfma(W, h).
__device__ __forceinline__ void consume_dense(const u64* __restrict__ hb, const bf16x8* w,
                                              floatx16& acc, int lane) {
  u64 q0[32], q1[32];
#pragma unroll
  for (int i = 0; i < 32; ++i) {
    q0[i] = aload64(hb + i * 128 + lane * 2);
    q1[i] = aload64(hb + i * 128 + lane * 2 + 1);
  }
#pragma unroll
  for (int i = 0; i < 32; ++i) {
    union {
      u64 qq[2];
      bf16x8 v;
    } u;
    u.qq[0] = q0[i];
    u.qq[1] = q1[i];
    acc = __builtin_amdgcn_mfma_f32_32x32x16_bf16(w[i], u.v, acc, 0, 0, 0);
  }
}

// 128 blocks x 256 threads (1 block/CU). unit=blockIdx&1, cg=blockIdx>>1.
// Private flags: pf0/pf1[cons 128][bt 2][src 64] u32 (128KB each).
__global__ __launch_bounds__(256, 1) void lstm_persist(
    const u16* __restrict__ Wcat, const float* __restrict__ bh,
    const u16* __restrict__ xb, u16* __restrict__ h0s, u16* __restrict__ h1s,
    u32* pf0, u32* pf1, float* __restrict__ out) {
  const int blk = blockIdx.x;
  const int unit = blk & 1;
  const int cg = blk >> 1;
  const int colbase = cg * 8;
  const int tid = threadIdx.x;
  const int wave = tid >> 6;
  const int bt = wave & 1;
  const int kh = wave >> 1;
  const int lane = tid & 63;
  const int l31 = lane & 31;
  const int lh = lane >> 5;

  __shared__ float ldsp[2 * 2 * 4 * 256];  // [buf][bt][rg][lane*4] = 16 KB

  // ---- W fragments into VGPRs (loop-invariant). A[row][k]: row=lane&31 -> W
  // row rp; k = kh*512 + i*16 + lh*8 + j (8 contiguous k -> one b128).
  bf16x8 w[32];
  {
    const int rp = l31;
    const u16* wbase = Wcat + ((size_t)unit * 2048 + (rp >> 3) * 512 + colbase + (rp & 7)) * 1024 +
                       kh * 512 + lh * 8;
#pragma unroll
    for (int i = 0; i < 32; ++i) w[i] = *(const bf16x8*)(wbase + i * 16);
  }

  // kh1-wave gate state (D[M=Wrow][N=batch]): lane (bt, l31, lh) owns batch
  // b = bt*32+l31, cols colbase + 4*lh + q (q=0..3); acc reg r = g*4+q.
  float bias[4][4];
#pragma unroll
  for (int g = 0; g < 4; ++g)
#pragma unroll
    for (int q = 0; q < 4; ++q)
      bias[g][q] = bh[unit * 2048 + g * 512 + colbase + 4 * lh + q];
  float creg[4] = {0.f, 0.f, 0.f, 0.f};

  // my private poll rows (one per bt): 64 consecutive u32.
  const u32* my_pf0 = pf0 + (blk * 2 + bt) * 64;
  const u32* my_pf1 = pf1 + (blk * 2 + bt) * 64;
  // producer fan-out targets: store to pf[c][bt][cg] for c = lane, lane+64.
  u32* fan_base = (unit ? pf1 : pf0);
  u32* fan_a = fan_base + ((size_t)lane * 2 + bt) * 64 + cg;
  u32* fan_b = fan_base + (((size_t)lane + 64) * 2 + bt) * 64 + cg;

  const size_t out_h_base = (size_t)T_ * BH;
  const size_t out_c_base = out_h_base + 2 * (size_t)BH;
  const int orow = bt * 32 + l31;
  const int ocol = colbase + 4 * lh;

  // publish piece index (R9-verified): p = bt*2048 + (cg>>1)*64 + (cg&1)*32
  // + l31, u64 half lh.
  const size_t pub_idx =
      ((size_t)bt * 2048 + (cg >> 1) * 64 + (cg & 1) * 32 + l31) * 2 + lh;

  for (int t = 0; t < T_; ++t) {
    floatx16 acc = {0.f, 0.f, 0.f, 0.f, 0.f, 0.f, 0.f, 0.f,
                    0.f, 0.f, 0.f, 0.f, 0.f, 0.f, 0.f, 0.f};
    const int buf = t & 1;
    float* lp = ldsp + (buf * 2 + bt) * 1024 + lane * 4;

    if (kh == 0) {
      if (unit == 0) {
        // x-half: plain dense loads from transposed xb (no dependency).
        const bf16x8* xp = (const bf16x8*)xb + (size_t)t * 4096 + bt * 2048 + lane;
#pragma unroll
        for (int i = 0; i < 32; ++i)
          acc = __builtin_amdgcn_mfma_f32_32x32x16_bf16(w[i], xp[i * 64], acc, 0, 0, 0);
      } else {
        // h0_t half (Wx1): the cross-layer hop.
        wave_wait(my_pf0, (u32)(t + 1), lane);
        consume_dense((const u64*)h0s + (size_t)(t & 3) * 8192 + (size_t)bt * 4096, w, acc, lane);
      }
      // partial -> LDS (double-buffered), one barrier per step.
#pragma unroll
      for (int rg = 0; rg < 4; ++rg)
        *(floatx4*)(lp + rg * 256) =
            floatx4{acc[rg * 4 + 0], acc[rg * 4 + 1], acc[rg * 4 + 2], acc[rg * 4 + 3]};
      __syncthreads();
    } else {
      // kh1: own-layer recurrence (h0_{t-1} / h1_{t-1}).
      if (t > 0) {
        if (unit == 0) {
          wave_wait(my_pf0, (u32)t, lane);
          consume_dense((const u64*)h0s + (size_t)((t - 1) & 3) * 8192 + (size_t)bt * 4096, w,
                        acc, lane);
        } else {
          wave_wait(my_pf1, (u32)t, lane);
          consume_dense((const u64*)h1s + (size_t)((t - 1) & 3) * 8192 + (size_t)bt * 4096, w,
                        acc, lane);
        }
      }
      __syncthreads();
      // add kh0 partial from LDS (same lane<->element mapping both waves)
#pragma unroll
      for (int rg = 0; rg < 4; ++rg) {
        floatx4 p = *(const floatx4*)(lp + rg * 256);
        acc[rg * 4 + 0] += p.x;
        acc[rg * 4 + 1] += p.y;
        acc[rg * 4 + 2] += p.z;
        acc[rg * 4 + 3] += p.w;
      }
      // gates in-register: gate g = acc[g*4+q], col q (of this lane's 4)
      float hn[4], cn[4];
#pragma unroll
      for (int q = 0; q < 4; ++q) {
        float pi = acc[q] + bias[0][q];
        float pf = acc[4 + q] + bias[1][q];
        float pg = acc[8 + q] + bias[2][q];
        float po = acc[12 + q] + bias[3][q];
        float ig = sigm(pi);
        float fg = sigm(pf);
        float gg = tanh_(pg);
        float og = sigm(po);
        cn[q] = fg * creg[q] + ig * gg;
        hn[q] = og * tanh_(cn[q]);
        creg[q] = cn[q];
      }

      // slot-reuse guard (unit0 only, R9-proven): before overwriting h0 slot
      // t&3 (holds h0_{t-4}, read by unit1 kh0 at step t-4), need unit1 past
      // step t-4 (pf1 >= t-3).
      if (unit == 0 && t >= 4) wave_wait(my_pf1, (u32)(t - 3), lane);

      // publish own 8B piece, drain, fan out flag copies (2 stores/lane).
      u64 pack = (u64)f2bf(hn[0]) | ((u64)f2bf(hn[1]) << 16) | ((u64)f2bf(hn[2]) << 32) |
                 ((u64)f2bf(hn[3]) << 48);
      u64* slot = (u64*)((unit ? h1s : h0s) + (size_t)(t & 3) * BH);
      astore64(slot + pub_idx, pack);
      asm volatile("s_waitcnt vmcnt(0)" ::: "memory");
      astore32(fan_a, (u32)(t + 1));
      astore32(fan_b, (u32)(t + 1));

      // off-chain d_out stores AFTER flag release.
      if (unit == 1)
        *(float4*)(out + (size_t)t * BH + (size_t)orow * 512 + ocol) =
            make_float4(hn[0], hn[1], hn[2], hn[3]);
      if (t == T_ - 1) {
        *(float4*)(out + out_h_base + (size_t)unit * BH + (size_t)orow * 512 + ocol) =
            make_float4(hn[0], hn[1], hn[2], hn[3]);
        *(float4*)(out + out_c_base + (size_t)unit * BH + (size_t)orow * 512 + ocol) =
            make_float4(cn[0], cn[1], cn[2], cn[3]);
      }
    }
  }
}

extern "C" void kernel_launch(void* const* d_in, const int* in_sizes, int n_in,
                              void* d_out, int out_size, void* d_ws, size_t ws_size,
                              hipStream_t stream) {
  const float* x = (const float*)d_in[0];
  const float* Wx = (const float*)d_in[1];
  const float* Wh = (const float*)d_in[2];
  const float* bh = (const float*)d_in[3];
  float* out = (float*)d_out;
  char* ws = (char*)d_ws;

  u16* Wcat = (u16*)ws;                                  // 8,388,608 B
  u16* xb = (u16*)(ws + 8388608);                        // 33,554,432 B
  u16* h0s = (u16*)(ws + 8388608 + 33554432);            // 262,144 B (4 slots)
  u16* h1s = (u16*)(ws + 8388608 + 33554432 + 262144);   // 262,144 B
  u32* pf0 = (u32*)(ws + 8388608 + 33554432 + 2 * 262144);         // 131,072 B
  u32* pf1 = (u32*)(ws + 8388608 + 33554432 + 2 * 262144 + 131072);  // 131,072 B

  conv_w_kernel<<<4096, 256, 0, stream>>>(Wx, Wh, Wcat);
  conv_x_kernel<<<8192, 256, 0, stream>>>(x, xb);
  init_flags<<<256, 256, 0, stream>>>(pf0);
  lstm_persist<<<128, 256, 0, stream>>>(Wcat, bh, xb, h0s, h1s, pf0, pf1, out);
}